// Round 1
// baseline (3144.691 us; speedup 1.0000x reference)
//
#include <hip/hip_runtime.h>
#include <math.h>

#define NN 50000
#define EE 250000
#define DD 256     // in_channels
#define HCC 256    // H*C
#define EDD 320    // edge_dim
#define TDD 64     // time dim

// ---- monotone float<->uint encoding for atomicMax on floats ----
static __device__ __forceinline__ unsigned fenc(float f) {
    unsigned u = __float_as_uint(f);
    return (u & 0x80000000u) ? ~u : (u | 0x80000000u);
}
static __device__ __forceinline__ float fdec(unsigned u) {
    unsigned v = (u & 0x80000000u) ? (u ^ 0x80000000u) : ~u;
    return __uint_as_float(v);
}

// ---- transpose weights into [k][col] layouts for coalesced GEMM B loads ----
__global__ void k_prep(const float* __restrict__ Wq, const float* __restrict__ bq,
                       const float* __restrict__ Wk, const float* __restrict__ bk,
                       const float* __restrict__ Wv, const float* __restrict__ bv,
                       const float* __restrict__ Wskip, const float* __restrict__ bskip,
                       const float* __restrict__ We,
                       float* __restrict__ WnT, float* __restrict__ bcat,
                       float* __restrict__ WeT) {
    int i = blockIdx.x * 256 + threadIdx.x;
    int stride = gridDim.x * 256;
    for (int idx = i; idx < 256 * 1024; idx += stride) {
        int k = idx >> 10, col = idx & 1023;
        int sel = col >> 8, o = col & 255;
        const float* W = (sel == 0) ? Wq : (sel == 1) ? Wk : (sel == 2) ? Wv : Wskip;
        WnT[idx] = W[o * 256 + k];
    }
    for (int idx = i; idx < 1024; idx += stride) {
        int sel = idx >> 8, o = idx & 255;
        const float* b = (sel == 0) ? bq : (sel == 1) ? bk : (sel == 2) ? bv : bskip;
        bcat[idx] = b[o];
    }
    for (int idx = i; idx < 320 * 256; idx += stride) {
        int k = idx >> 8, o = idx & 255;
        WeT[idx] = We[o * 320 + k];
    }
}

// ---- zero-init accumulators (harness does NOT re-zero ws between replays) ----
__global__ void k_init(float* __restrict__ acc, float* __restrict__ denom,
                       unsigned* __restrict__ menc) {
    int i = blockIdx.x * 256 + threadIdx.x;
    int stride = gridDim.x * 256;
    for (int idx = i; idx < NN * 256; idx += stride) acc[idx] = 0.f;
    for (int idx = i; idx < NN * 4; idx += stride) { denom[idx] = 0.f; menc[idx] = 0u; }
}

// ---- fused q/k/v/skip GEMM: [50000 x 256] @ [256 x 1024] ----
// tile 64x64, 256 threads (16x16), 4x4 per thread, K-step 32
__global__ __launch_bounds__(256) void k_node_gemm(
        const float* __restrict__ x, const float* __restrict__ WnT,
        const float* __restrict__ bcat,
        float* __restrict__ q, float* __restrict__ kbuf, float* __restrict__ vbuf,
        float* __restrict__ outskip) {
    __shared__ float At[64][33];
    __shared__ float Bt[32][65];
    int rb = blockIdx.x * 64;
    int cb = blockIdx.y * 64;  // global col 0..1023
    int tid = threadIdx.x;
    int ty = tid >> 4, tx = tid & 15;
    float acc[4][4] = {};
    for (int k0 = 0; k0 < 256; k0 += 32) {
        #pragma unroll
        for (int l = 0; l < 8; ++l) {
            int idx = tid + l * 256;
            int kk = idx & 31, r = idx >> 5;
            int row = rb + r;
            At[r][kk] = (row < NN) ? x[(size_t)row * 256 + k0 + kk] : 0.f;
        }
        #pragma unroll
        for (int l = 0; l < 8; ++l) {
            int idx = tid + l * 256;
            int c = idx & 63, kk = idx >> 6;
            Bt[kk][c] = WnT[(size_t)(k0 + kk) * 1024 + cb + c];
        }
        __syncthreads();
        #pragma unroll
        for (int k = 0; k < 32; ++k) {
            float a0 = At[ty][k], a1 = At[ty + 16][k], a2 = At[ty + 32][k], a3 = At[ty + 48][k];
            float b0 = Bt[k][tx], b1 = Bt[k][tx + 16], b2 = Bt[k][tx + 32], b3 = Bt[k][tx + 48];
            acc[0][0] += a0 * b0; acc[0][1] += a0 * b1; acc[0][2] += a0 * b2; acc[0][3] += a0 * b3;
            acc[1][0] += a1 * b0; acc[1][1] += a1 * b1; acc[1][2] += a1 * b2; acc[1][3] += a1 * b3;
            acc[2][0] += a2 * b0; acc[2][1] += a2 * b1; acc[2][2] += a2 * b2; acc[2][3] += a2 * b3;
            acc[3][0] += a3 * b0; acc[3][1] += a3 * b1; acc[3][2] += a3 * b2; acc[3][3] += a3 * b3;
        }
        __syncthreads();
    }
    int sel = cb >> 8;          // 0=q 1=k 2=v 3=skip
    int cin = cb & 255;
    float* dst = (sel == 0) ? q : (sel == 1) ? kbuf : (sel == 2) ? vbuf : outskip;
    #pragma unroll
    for (int i = 0; i < 4; ++i) {
        int row = rb + ty + 16 * i;
        if (row >= NN) continue;
        #pragma unroll
        for (int j = 0; j < 4; ++j) {
            int c = tx + 16 * j;
            dst[(size_t)row * 256 + cin + c] = acc[i][j] + bcat[cb + c];
        }
    }
}

// ---- edge GEMM: e = [cos(rel_t*w+b) | msg] @ WeT, plus alpha + segment max ----
// 16 edges x 256 cols per block, K=320 step 32
__global__ __launch_bounds__(256) void k_edge_a(
        const float* __restrict__ msg, const float* __restrict__ t_arr,
        const float* __restrict__ last_update, const int* __restrict__ ei,
        const float* __restrict__ time_w, const float* __restrict__ time_b,
        const float* __restrict__ WeT,
        const float* __restrict__ q, const float* __restrict__ kbuf,
        float* __restrict__ ebuf, float* __restrict__ alpha,
        unsigned* __restrict__ menc) {
    __shared__ float At[16][33];
    __shared__ float Bt[32][256];
    __shared__ float s_relt[16];
    __shared__ int s_src[16], s_dst[16];
    int e0 = blockIdx.x * 16;
    int tid = threadIdx.x;
    if (tid < 16) {
        int ed = e0 + tid;
        int s = ei[ed], d = ei[EE + ed];
        s_src[tid] = s; s_dst[tid] = d;
        s_relt[tid] = last_update[s] - t_arr[ed];
    }
    __syncthreads();
    int ty = tid >> 4, tx = tid & 15;  // ty = edge row, tx = col lane
    float acc[16] = {};
    for (int k0 = 0; k0 < 320; k0 += 32) {
        #pragma unroll
        for (int l = 0; l < 2; ++l) {
            int idx = tid + l * 256;
            int kk = idx & 31, r = idx >> 5;
            int col = k0 + kk;
            float val;
            if (col < TDD) val = cosf(s_relt[r] * time_w[col] + time_b[col]);
            else val = msg[(size_t)(e0 + r) * 256 + (col - 64)];
            At[r][kk] = val;
        }
        #pragma unroll
        for (int l = 0; l < 8; ++l) {
            int idx = tid + l * 256;
            int c4 = idx & 63, kk = idx >> 6;
            *(float4*)&Bt[kk][c4 * 4] =
                *(const float4*)(WeT + (size_t)(k0 + kk) * 256 + c4 * 4);
        }
        __syncthreads();
        #pragma unroll
        for (int k = 0; k < 32; ++k) {
            float a = At[ty][k];
            #pragma unroll
            for (int j = 0; j < 16; ++j) acc[j] += a * Bt[k][tx + 16 * j];
        }
        __syncthreads();
    }
    int edge = e0 + ty;
    int src = s_src[ty], dst = s_dst[ty];
    float part[4] = {0.f, 0.f, 0.f, 0.f};
    #pragma unroll
    for (int j = 0; j < 16; ++j) {
        int col = tx + 16 * j;
        ebuf[(size_t)edge * 256 + col] = acc[j];
        float qv = q[(size_t)dst * 256 + col];
        float kv = kbuf[(size_t)src * 256 + col];
        part[j >> 2] += qv * (kv + acc[j]);
    }
    #pragma unroll
    for (int m2 = 1; m2 < 16; m2 <<= 1) {
        #pragma unroll
        for (int h = 0; h < 4; ++h) part[h] += __shfl_xor(part[h], m2);
    }
    if (tx < 4) {
        float a = part[tx] * 0.125f;  // / sqrt(64)
        alpha[(size_t)edge * 4 + tx] = a;
        atomicMax(&menc[(size_t)dst * 4 + tx], fenc(a));
    }
}

// ---- scatter: acc[dst] += exp(alpha-m)*(v[src]+e); denom[dst] += exp ----
__global__ __launch_bounds__(256) void k_edge_b(
        const float* __restrict__ ebuf, const float* __restrict__ vbuf,
        const float* __restrict__ alpha, const unsigned* __restrict__ menc,
        const int* __restrict__ ei,
        float* __restrict__ denom, float* __restrict__ acc) {
    int e0 = blockIdx.x * 16;
    int lane = threadIdx.x & 63;  // 64 col-threads x float4
    int er = threadIdx.x >> 6;    // 4 edge rows in parallel
    int c0 = lane * 4;
    int h = lane >> 4;
    #pragma unroll
    for (int rr = 0; rr < 4; ++rr) {
        int edge = e0 + rr * 4 + er;
        int src = ei[edge], dst = ei[EE + edge];
        float m = fdec(menc[(size_t)dst * 4 + h]);
        float ex = __expf(alpha[(size_t)edge * 4 + h] - m);
        float4 vv = *(const float4*)(vbuf + (size_t)src * 256 + c0);
        float4 ee = *(const float4*)(ebuf + (size_t)edge * 256 + c0);
        float* a = acc + (size_t)dst * 256 + c0;
        atomicAdd(a + 0, (vv.x + ee.x) * ex);
        atomicAdd(a + 1, (vv.y + ee.y) * ex);
        atomicAdd(a + 2, (vv.z + ee.z) * ex);
        atomicAdd(a + 3, (vv.w + ee.w) * ex);
        if ((lane & 15) == 0) atomicAdd(&denom[(size_t)dst * 4 + h], ex);
    }
}

// ---- finalize: out = skip + acc/(denom+1e-16) ----
__global__ void k_final(const float* __restrict__ acc, const float* __restrict__ denom,
                        float* __restrict__ out) {
    int i = blockIdx.x * 256 + threadIdx.x;
    int stride = gridDim.x * 256;
    for (int idx = i; idx < NN * 256; idx += stride) {
        int n = idx >> 8, h = (idx & 255) >> 6;
        out[idx] = out[idx] + acc[idx] / (denom[n * 4 + h] + 1e-16f);
    }
}

extern "C" void kernel_launch(void* const* d_in, const int* in_sizes, int n_in,
                              void* d_out, int out_size, void* d_ws, size_t ws_size,
                              hipStream_t stream) {
    const float* x        = (const float*)d_in[0];
    const float* last_upd = (const float*)d_in[1];
    const float* t_arr    = (const float*)d_in[2];
    const float* msg      = (const float*)d_in[3];
    const int*   ei       = (const int*)d_in[4];
    const float* time_w   = (const float*)d_in[5];
    const float* time_b   = (const float*)d_in[6];
    const float* Wq = (const float*)d_in[7];  const float* bq = (const float*)d_in[8];
    const float* Wk = (const float*)d_in[9];  const float* bk = (const float*)d_in[10];
    const float* Wv = (const float*)d_in[11]; const float* bv = (const float*)d_in[12];
    const float* We = (const float*)d_in[13];
    const float* Wsk = (const float*)d_in[14]; const float* bsk = (const float*)d_in[15];
    float* out = (float*)d_out;
    float* ws = (float*)d_ws;

    size_t off = 0;
    float* q     = ws + off; off += (size_t)NN * 256;
    float* kbuf  = ws + off; off += (size_t)NN * 256;
    float* vbuf  = ws + off; off += (size_t)NN * 256;
    float* accb  = ws + off; off += (size_t)NN * 256;
    float* ebuf  = ws + off; off += (size_t)EE * 256;
    float* alpha = ws + off; off += (size_t)EE * 4;
    float* denom = ws + off; off += (size_t)NN * 4;
    unsigned* menc = (unsigned*)(ws + off); off += (size_t)NN * 4;
    float* WnT   = ws + off; off += 256 * 1024;
    float* bcat  = ws + off; off += 1024;
    float* WeT   = ws + off; off += 320 * 256;
    // total ~468 MB of ws required

    k_prep<<<dim3(256), dim3(256), 0, stream>>>(Wq, bq, Wk, bk, Wv, bv, Wsk, bsk, We,
                                                WnT, bcat, WeT);
    k_init<<<dim3(2048), dim3(256), 0, stream>>>(accb, denom, menc);
    k_node_gemm<<<dim3(782, 16), dim3(256), 0, stream>>>(x, WnT, bcat, q, kbuf, vbuf, out);
    k_edge_a<<<dim3(EE / 16), dim3(256), 0, stream>>>(msg, t_arr, last_upd, ei,
                                                      time_w, time_b, WeT, q, kbuf,
                                                      ebuf, alpha, menc);
    k_edge_b<<<dim3(EE / 16), dim3(256), 0, stream>>>(ebuf, vbuf, alpha, menc, ei,
                                                      denom, accb);
    k_final<<<dim3(2048), dim3(256), 0, stream>>>(accb, denom, out);
}

// Round 2
// 1302.835 us; speedup vs baseline: 2.4137x; 2.4137x over previous
//
#include <hip/hip_runtime.h>
#include <math.h>

#define NN 50000
#define EE 250000
#define NPAD 50048
#define EPAD 250048

typedef float f32x4 __attribute__((ext_vector_type(4)));
typedef __bf16 bf16x8 __attribute__((ext_vector_type(8)));

// f32 -> bf16 (RNE) and back, header-independent
static __device__ __forceinline__ ushort f2b(float f) {
    unsigned u = __float_as_uint(f);
    unsigned r = (u + 0x7FFFu + ((u >> 16) & 1u)) >> 16;
    return (ushort)r;
}
static __device__ __forceinline__ float b2f(ushort u) {
    return __uint_as_float(((unsigned)u) << 16);
}
// monotone float<->uint encoding for atomicMax on floats
static __device__ __forceinline__ unsigned fenc(float f) {
    unsigned u = __float_as_uint(f);
    return (u & 0x80000000u) ? ~u : (u | 0x80000000u);
}
static __device__ __forceinline__ float fdec(unsigned u) {
    unsigned v = (u & 0x80000000u) ? (u ^ 0x80000000u) : ~u;
    return __uint_as_float(v);
}

// ---- weights -> bf16 (W stays [out][in] = [n][k], which is exactly the
// n-major/k-inner layout our B-fragments want; no transpose needed) ----
__global__ void k_prep_w(const float* __restrict__ Wq, const float* __restrict__ bq,
                         const float* __restrict__ Wk, const float* __restrict__ bk,
                         const float* __restrict__ Wv, const float* __restrict__ bv,
                         const float* __restrict__ Wskip, const float* __restrict__ bskip,
                         const float* __restrict__ We,
                         ushort* __restrict__ Wnb, ushort* __restrict__ Web,
                         float* __restrict__ bcat) {
    int i = blockIdx.x * 256 + threadIdx.x;
    int st = gridDim.x * 256;
    for (int idx = i; idx < 1024 * 256; idx += st) {
        int n = idx >> 8, kk = idx & 255;
        int sel = n >> 8, o = n & 255;
        const float* W = (sel == 0) ? Wq : (sel == 1) ? Wk : (sel == 2) ? Wv : Wskip;
        Wnb[idx] = f2b(W[o * 256 + kk]);
    }
    for (int idx = i; idx < 256 * 320; idx += st) Web[idx] = f2b(We[idx]);
    for (int idx = i; idx < 1024; idx += st) {
        int sel = idx >> 8, o = idx & 255;
        const float* b = (sel == 0) ? bq : (sel == 1) ? bk : (sel == 2) ? bv : bskip;
        bcat[idx] = b[o];
    }
}

// ---- x -> bf16, padded to NPAD rows (zero tail) ----
__global__ void k_prep_x(const float* __restrict__ x, ushort* __restrict__ xb) {
    int i = blockIdx.x * 256 + threadIdx.x;
    int st = gridDim.x * 256;
    for (int ch = i; ch < NPAD * 32; ch += st) {
        int row = ch >> 5, co = (ch & 31) * 8;
        union { ushort u[8]; uint4 v; } s;
        if (row < NN) {
            float4 a = *(const float4*)(x + (size_t)row * 256 + co);
            float4 b = *(const float4*)(x + (size_t)row * 256 + co + 4);
            s.u[0] = f2b(a.x); s.u[1] = f2b(a.y); s.u[2] = f2b(a.z); s.u[3] = f2b(a.w);
            s.u[4] = f2b(b.x); s.u[5] = f2b(b.y); s.u[6] = f2b(b.z); s.u[7] = f2b(b.w);
        } else {
            s.v = make_uint4(0, 0, 0, 0);
        }
        *(uint4*)(xb + (size_t)row * 256 + co) = s.v;
    }
}

// ---- edge_attr = [cos(rel_t*w+b) | msg] -> bf16 [EPAD][320] ----
__global__ void k_prep_ea(const float* __restrict__ msg, const float* __restrict__ t_arr,
                          const float* __restrict__ lu, const int* __restrict__ ei,
                          const float* __restrict__ tw, const float* __restrict__ tb,
                          ushort* __restrict__ ea) {
    int i = blockIdx.x * 256 + threadIdx.x;
    int st = gridDim.x * 256;
    for (int ch = i; ch < EPAD * 40; ch += st) {
        int e = ch / 40, c8 = (ch % 40) * 8;
        union { ushort u[8]; uint4 v; } s;
        if (e < EE) {
            if (c8 < 64) {
                float rt = lu[ei[e]] - t_arr[e];
                #pragma unroll
                for (int j = 0; j < 8; ++j)
                    s.u[j] = f2b(cosf(rt * tw[c8 + j] + tb[c8 + j]));
            } else {
                float4 a = *(const float4*)(msg + (size_t)e * 256 + (c8 - 64));
                float4 b = *(const float4*)(msg + (size_t)e * 256 + (c8 - 64) + 4);
                s.u[0] = f2b(a.x); s.u[1] = f2b(a.y); s.u[2] = f2b(a.z); s.u[3] = f2b(a.w);
                s.u[4] = f2b(b.x); s.u[5] = f2b(b.y); s.u[6] = f2b(b.z); s.u[7] = f2b(b.w);
            }
        } else {
            s.v = make_uint4(0, 0, 0, 0);
        }
        *(uint4*)(ea + (size_t)e * 320 + c8) = s.v;
    }
}

// ---- zero accumulators each launch (atomics accumulate) ----
__global__ void k_init(float* __restrict__ acc, float* __restrict__ denom,
                       unsigned* __restrict__ menc) {
    int i = blockIdx.x * 256 + threadIdx.x;
    int st = gridDim.x * 256;
    for (int idx = i; idx < NN * 64; idx += st)
        *(float4*)(acc + (size_t)idx * 4) = make_float4(0.f, 0.f, 0.f, 0.f);
    for (int idx = i; idx < NN * 4; idx += st) { denom[idx] = 0.f; menc[idx] = 0u; }
}

// ---- node GEMM: [NPAD x 256] @ [256 x 1024]^T(n-major) via bf16 MFMA ----
// 128x128 tile, 4 waves of 64x64, XOR-swizzled LDS (chunk c of row r at c^(r&7))
__global__ __launch_bounds__(256) void k_node_mfma(
        const ushort* __restrict__ xb, const ushort* __restrict__ Wnb,
        const float* __restrict__ bcat,
        ushort* __restrict__ qb, ushort* __restrict__ kb, ushort* __restrict__ vb,
        float* __restrict__ out) {
    __shared__ ushort As[128 * 64];
    __shared__ ushort Bs[128 * 64];
    int tid = threadIdx.x;
    int lane = tid & 63, wid = tid >> 6;
    int wr = wid >> 1, wc = wid & 1;
    int li = lane & 15, g = lane >> 4;
    int bm = blockIdx.x, bn = blockIdx.y;
    f32x4 acc[4][4] = {};
    for (int k0 = 0; k0 < 256; k0 += 64) {
        __syncthreads();
        #pragma unroll
        for (int i = 0; i < 4; ++i) {
            int ch = tid + i * 256;
            int r = ch >> 3, c = ch & 7;
            uint4 va = *(const uint4*)(xb + (size_t)(bm * 128 + r) * 256 + k0 + c * 8);
            *(uint4*)&As[r * 64 + ((c ^ (r & 7)) * 8)] = va;
            uint4 vb4 = *(const uint4*)(Wnb + (size_t)(bn * 128 + r) * 256 + k0 + c * 8);
            *(uint4*)&Bs[r * 64 + ((c ^ (r & 7)) * 8)] = vb4;
        }
        __syncthreads();
        #pragma unroll
        for (int kk = 0; kk < 2; ++kk) {
            bf16x8 a[4], b[4];
            #pragma unroll
            for (int m = 0; m < 4; ++m) {
                int r = wr * 64 + m * 16 + li;
                a[m] = *(const bf16x8*)&As[r * 64 + (((kk * 4 + g) ^ (r & 7)) * 8)];
            }
            #pragma unroll
            for (int n = 0; n < 4; ++n) {
                int r = wc * 64 + n * 16 + li;
                b[n] = *(const bf16x8*)&Bs[r * 64 + (((kk * 4 + g) ^ (r & 7)) * 8)];
            }
            #pragma unroll
            for (int m = 0; m < 4; ++m)
                #pragma unroll
                for (int n = 0; n < 4; ++n)
                    acc[m][n] = __builtin_amdgcn_mfma_f32_16x16x32_bf16(a[m], b[n], acc[m][n], 0, 0, 0);
        }
    }
    // epilogue: D layout row=(lane>>4)*4+reg, col=lane&15 (guide-verified)
    int sel = bn >> 1;
    int cbase = (bn & 1) * 128;
    ushort* dstb = (sel == 0) ? qb : (sel == 1) ? kb : vb;
    #pragma unroll
    for (int m = 0; m < 4; ++m) {
        #pragma unroll
        for (int r = 0; r < 4; ++r) {
            int row = bm * 128 + wr * 64 + m * 16 + g * 4 + r;
            if (row >= NN) continue;
            #pragma unroll
            for (int n = 0; n < 4; ++n) {
                int coll = wc * 64 + n * 16 + li;
                float val = acc[m][n][r] + bcat[bn * 128 + coll];
                int cin = cbase + coll;
                if (sel < 3) dstb[(size_t)row * 256 + cin] = f2b(val);
                else         out[(size_t)row * 256 + cin] = val;
            }
        }
    }
}

// ---- edge GEMM: e = ea @ We^T (64 edges x 256 cols/block) + fused alpha ----
// 4 waves: wave(wr,wc) owns edges [32wr,32wr+32) x cols [128wc,128wc+128)
// -> heads {2wc, 2wc+1} exclusively, so alpha reduces within one wave.
__global__ __launch_bounds__(256) void k_edge_mfma(
        const ushort* __restrict__ ea, const ushort* __restrict__ Web,
        const ushort* __restrict__ qb, const ushort* __restrict__ kb,
        const int* __restrict__ ei,
        ushort* __restrict__ ebuf, float* __restrict__ alpha,
        unsigned* __restrict__ menc) {
    __shared__ ushort As[64 * 64];
    __shared__ ushort Bs[256 * 64];
    __shared__ int s_src[64], s_dst[64];
    int tid = threadIdx.x;
    int lane = tid & 63, wid = tid >> 6;
    int wr = wid >> 1, wc = wid & 1;
    int li = lane & 15, g = lane >> 4;
    int e0 = blockIdx.x * 64;
    if (tid < 64) {
        int e = e0 + tid;
        if (e >= EE) e = EE - 1;  // clamp; tail edges never write
        s_src[tid] = ei[e];
        s_dst[tid] = ei[EE + e];
    }
    f32x4 acc[2][8] = {};
    for (int k0 = 0; k0 < 320; k0 += 64) {
        __syncthreads();
        #pragma unroll
        for (int i = 0; i < 2; ++i) {
            int ch = tid + i * 256;
            int r = ch >> 3, c = ch & 7;
            uint4 va = *(const uint4*)(ea + (size_t)(e0 + r) * 320 + k0 + c * 8);
            *(uint4*)&As[r * 64 + ((c ^ (r & 7)) * 8)] = va;
        }
        #pragma unroll
        for (int i = 0; i < 8; ++i) {
            int ch = tid + i * 256;
            int r = ch >> 3, c = ch & 7;
            uint4 vb4 = *(const uint4*)(Web + (size_t)r * 320 + k0 + c * 8);
            *(uint4*)&Bs[r * 64 + ((c ^ (r & 7)) * 8)] = vb4;
        }
        __syncthreads();
        #pragma unroll
        for (int kk = 0; kk < 2; ++kk) {
            bf16x8 a[2], b[8];
            #pragma unroll
            for (int m = 0; m < 2; ++m) {
                int r = wr * 32 + m * 16 + li;
                a[m] = *(const bf16x8*)&As[r * 64 + (((kk * 4 + g) ^ (r & 7)) * 8)];
            }
            #pragma unroll
            for (int n = 0; n < 8; ++n) {
                int r = wc * 128 + n * 16 + li;
                b[n] = *(const bf16x8*)&Bs[r * 64 + (((kk * 4 + g) ^ (r & 7)) * 8)];
            }
            #pragma unroll
            for (int m = 0; m < 2; ++m)
                #pragma unroll
                for (int n = 0; n < 8; ++n)
                    acc[m][n] = __builtin_amdgcn_mfma_f32_16x16x32_bf16(a[m], b[n], acc[m][n], 0, 0, 0);
        }
    }
    // epilogue: write e (bf16) and alpha = q[dst].(k[src]+e)/8 per head
    #pragma unroll
    for (int m = 0; m < 2; ++m) {
        #pragma unroll
        for (int r = 0; r < 4; ++r) {
            int el = wr * 32 + m * 16 + g * 4 + r;
            int edge = e0 + el;
            bool live = (edge < EE);
            int src = s_src[el], dst = s_dst[el];
            float p0 = 0.f, p1 = 0.f;
            #pragma unroll
            for (int n = 0; n < 8; ++n) {
                int col = wc * 128 + n * 16 + li;
                float ev = acc[m][n][r];
                if (live) ebuf[(size_t)edge * 256 + col] = f2b(ev);
                float qv = b2f(qb[(size_t)dst * 256 + col]);
                float kv = b2f(kb[(size_t)src * 256 + col]);
                float tt = qv * (kv + ev);
                if (n < 4) p0 += tt; else p1 += tt;
            }
            #pragma unroll
            for (int msk = 1; msk < 16; msk <<= 1) {
                p0 += __shfl_xor(p0, msk);
                p1 += __shfl_xor(p1, msk);
            }
            if (li < 2 && live) {
                float av = ((li == 0) ? p0 : p1) * 0.125f;
                int h = wc * 2 + li;
                alpha[(size_t)edge * 4 + h] = av;
                atomicMax(&menc[(size_t)dst * 4 + h], fenc(av));
            }
        }
    }
}

// ---- scatter: acc[dst] += exp(alpha-m)*(v[src]+e); denom[dst] += exp ----
__global__ __launch_bounds__(256) void k_edge_b(
        const ushort* __restrict__ ebuf, const ushort* __restrict__ vb,
        const float* __restrict__ alpha, const unsigned* __restrict__ menc,
        const int* __restrict__ ei,
        float* __restrict__ denom, float* __restrict__ acc) {
    int wid = threadIdx.x >> 6, lane = threadIdx.x & 63;
    int edge = blockIdx.x * 4 + wid;
    if (edge >= EE) return;
    int src = ei[edge], dst = ei[EE + edge];
    int h = lane >> 4;
    float m = fdec(menc[(size_t)dst * 4 + h]);
    float ex = __expf(alpha[(size_t)edge * 4 + h] - m);
    int c0 = lane * 4;
    ushort4 ev = *(const ushort4*)(ebuf + (size_t)edge * 256 + c0);
    ushort4 vv = *(const ushort4*)(vb + (size_t)src * 256 + c0);
    float* a = acc + (size_t)dst * 256 + c0;
    atomicAdd(a + 0, (b2f(vv.x) + b2f(ev.x)) * ex);
    atomicAdd(a + 1, (b2f(vv.y) + b2f(ev.y)) * ex);
    atomicAdd(a + 2, (b2f(vv.z) + b2f(ev.z)) * ex);
    atomicAdd(a + 3, (b2f(vv.w) + b2f(ev.w)) * ex);
    if ((lane & 15) == 0) atomicAdd(&denom[(size_t)dst * 4 + h], ex);
}

// ---- finalize: out = skip + acc/(denom+1e-16) ----
__global__ void k_final(const float* __restrict__ acc, const float* __restrict__ denom,
                        float* __restrict__ out) {
    int i = blockIdx.x * 256 + threadIdx.x;
    int st = gridDim.x * 256;
    for (int idx = i; idx < NN * 256; idx += st) {
        int n = idx >> 8, h = (idx & 255) >> 6;
        out[idx] = out[idx] + acc[idx] / (denom[n * 4 + h] + 1e-16f);
    }
}

extern "C" void kernel_launch(void* const* d_in, const int* in_sizes, int n_in,
                              void* d_out, int out_size, void* d_ws, size_t ws_size,
                              hipStream_t stream) {
    const float* x        = (const float*)d_in[0];
    const float* last_upd = (const float*)d_in[1];
    const float* t_arr    = (const float*)d_in[2];
    const float* msg      = (const float*)d_in[3];
    const int*   ei       = (const int*)d_in[4];
    const float* time_w   = (const float*)d_in[5];
    const float* time_b   = (const float*)d_in[6];
    const float* Wq = (const float*)d_in[7];  const float* bq = (const float*)d_in[8];
    const float* Wk = (const float*)d_in[9];  const float* bk = (const float*)d_in[10];
    const float* Wv = (const float*)d_in[11]; const float* bv = (const float*)d_in[12];
    const float* We = (const float*)d_in[13];
    const float* Wsk = (const float*)d_in[14]; const float* bsk = (const float*)d_in[15];
    float* out = (float*)d_out;
    char* base = (char*)d_ws;

    size_t off = 0;
    auto carve = [&](size_t bytes) {
        void* p = base + off;
        off += (bytes + 255) & ~(size_t)255;
        return p;
    };
    ushort* xb    = (ushort*)carve((size_t)NPAD * 256 * 2);
    ushort* Wnb   = (ushort*)carve((size_t)1024 * 256 * 2);
    ushort* Web   = (ushort*)carve((size_t)256 * 320 * 2);
    float*  bcat  = (float*) carve(1024 * 4);
    ushort* eab   = (ushort*)carve((size_t)EPAD * 320 * 2);
    ushort* qb    = (ushort*)carve((size_t)NN * 256 * 2);
    ushort* kb    = (ushort*)carve((size_t)NN * 256 * 2);
    ushort* vb    = (ushort*)carve((size_t)NN * 256 * 2);
    ushort* ebuf  = (ushort*)carve((size_t)EE * 256 * 2);
    float*  alpha = (float*) carve((size_t)EE * 4 * 4);
    float*  denom = (float*) carve((size_t)NN * 4 * 4);
    unsigned* menc= (unsigned*)carve((size_t)NN * 4 * 4);
    float*  accb  = (float*) carve((size_t)NN * 256 * 4);

    k_prep_w<<<dim3(512), dim3(256), 0, stream>>>(Wq, bq, Wk, bk, Wv, bv, Wsk, bsk, We,
                                                  Wnb, Web, bcat);
    k_prep_x<<<dim3(2048), dim3(256), 0, stream>>>(x, xb);
    k_prep_ea<<<dim3(4096), dim3(256), 0, stream>>>(msg, t_arr, last_upd, ei,
                                                    time_w, time_b, eab);
    k_init<<<dim3(2048), dim3(256), 0, stream>>>(accb, denom, menc);
    k_node_mfma<<<dim3(391, 8), dim3(256), 0, stream>>>(xb, Wnb, bcat, qb, kb, vb, out);
    k_edge_mfma<<<dim3(3907), dim3(256), 0, stream>>>(eab, Web, qb, kb, ei,
                                                      ebuf, alpha, menc);
    k_edge_b<<<dim3(62500), dim3(256), 0, stream>>>(ebuf, vb, alpha, menc, ei,
                                                    denom, accb);
    k_final<<<dim3(2048), dim3(256), 0, stream>>>(accb, denom, out);
}

// Round 3
// 649.977 us; speedup vs baseline: 4.8382x; 2.0044x over previous
//
#include <hip/hip_runtime.h>
#include <math.h>

#define NN 50000
#define EE 250000
#define NPAD 50048
#define EPAD 250048

typedef float f32x4 __attribute__((ext_vector_type(4)));
typedef __bf16 bf16x8 __attribute__((ext_vector_type(8)));

// f32 -> bf16 (RNE) and back, header-independent
static __device__ __forceinline__ ushort f2b(float f) {
    unsigned u = __float_as_uint(f);
    unsigned r = (u + 0x7FFFu + ((u >> 16) & 1u)) >> 16;
    return (ushort)r;
}
static __device__ __forceinline__ float b2f(ushort u) {
    return __uint_as_float(((unsigned)u) << 16);
}

// ---- weights -> bf16 (W stays [out][in] = [n][k]; B-fragments want n-major) ----
__global__ void k_prep_w(const float* __restrict__ Wq, const float* __restrict__ bq,
                         const float* __restrict__ Wk, const float* __restrict__ bk,
                         const float* __restrict__ Wv, const float* __restrict__ bv,
                         const float* __restrict__ Wskip, const float* __restrict__ bskip,
                         const float* __restrict__ We,
                         ushort* __restrict__ Wnb, ushort* __restrict__ Web,
                         float* __restrict__ bcat) {
    int i = blockIdx.x * 256 + threadIdx.x;
    int st = gridDim.x * 256;
    for (int idx = i; idx < 1024 * 256; idx += st) {
        int n = idx >> 8, kk = idx & 255;
        int sel = n >> 8, o = n & 255;
        const float* W = (sel == 0) ? Wq : (sel == 1) ? Wk : (sel == 2) ? Wv : Wskip;
        Wnb[idx] = f2b(W[o * 256 + kk]);
    }
    for (int idx = i; idx < 256 * 320; idx += st) Web[idx] = f2b(We[idx]);
    for (int idx = i; idx < 1024; idx += st) {
        int sel = idx >> 8, o = idx & 255;
        const float* b = (sel == 0) ? bq : (sel == 1) ? bk : (sel == 2) ? bv : bskip;
        bcat[idx] = b[o];
    }
}

// ---- x -> bf16, padded to NPAD rows (zero tail) ----
__global__ void k_prep_x(const float* __restrict__ x, ushort* __restrict__ xb) {
    int i = blockIdx.x * 256 + threadIdx.x;
    int st = gridDim.x * 256;
    for (int ch = i; ch < NPAD * 32; ch += st) {
        int row = ch >> 5, co = (ch & 31) * 8;
        union { ushort u[8]; uint4 v; } s;
        if (row < NN) {
            float4 a = *(const float4*)(x + (size_t)row * 256 + co);
            float4 b = *(const float4*)(x + (size_t)row * 256 + co + 4);
            s.u[0] = f2b(a.x); s.u[1] = f2b(a.y); s.u[2] = f2b(a.z); s.u[3] = f2b(a.w);
            s.u[4] = f2b(b.x); s.u[5] = f2b(b.y); s.u[6] = f2b(b.z); s.u[7] = f2b(b.w);
        } else {
            s.v = make_uint4(0, 0, 0, 0);
        }
        *(uint4*)(xb + (size_t)row * 256 + co) = s.v;
    }
}

// ---- edge_attr = [cos(rel_t*w+b) | msg] -> bf16 [EPAD][320] ----
__global__ void k_prep_ea(const float* __restrict__ msg, const float* __restrict__ t_arr,
                          const float* __restrict__ lu, const int* __restrict__ ei,
                          const float* __restrict__ tw, const float* __restrict__ tb,
                          ushort* __restrict__ ea) {
    int i = blockIdx.x * 256 + threadIdx.x;
    int st = gridDim.x * 256;
    for (int ch = i; ch < EPAD * 40; ch += st) {
        int e = ch / 40, c8 = (ch % 40) * 8;
        union { ushort u[8]; uint4 v; } s;
        if (e < EE) {
            if (c8 < 64) {
                float rt = lu[ei[e]] - t_arr[e];
                #pragma unroll
                for (int j = 0; j < 8; ++j)
                    s.u[j] = f2b(cosf(rt * tw[c8 + j] + tb[c8 + j]));
            } else {
                float4 a = *(const float4*)(msg + (size_t)e * 256 + (c8 - 64));
                float4 b = *(const float4*)(msg + (size_t)e * 256 + (c8 - 64) + 4);
                s.u[0] = f2b(a.x); s.u[1] = f2b(a.y); s.u[2] = f2b(a.z); s.u[3] = f2b(a.w);
                s.u[4] = f2b(b.x); s.u[5] = f2b(b.y); s.u[6] = f2b(b.z); s.u[7] = f2b(b.w);
            }
        } else {
            s.v = make_uint4(0, 0, 0, 0);
        }
        *(uint4*)(ea + (size_t)e * 320 + c8) = s.v;
    }
}

// ---- counting sort by dst: zero -> hist -> scan -> scatter ----
__global__ void k_zero(unsigned* __restrict__ deg) {
    int i = blockIdx.x * 256 + threadIdx.x;
    if (i < NN) deg[i] = 0u;
}

__global__ void k_hist(const int* __restrict__ ei, unsigned* __restrict__ deg) {
    int i = blockIdx.x * 256 + threadIdx.x;
    if (i < EE) atomicAdd(&deg[ei[EE + i]], 1u);
}

__global__ __launch_bounds__(1024) void k_scan(const unsigned* __restrict__ deg,
                                               unsigned* __restrict__ offs,
                                               unsigned* __restrict__ cursor) {
    __shared__ unsigned part[1024];
    int t = threadIdx.x;
    const int CH = (NN + 1023) / 1024;  // 49
    int b0 = t * CH;
    unsigned s = 0;
    for (int i = 0; i < CH; ++i) { int idx = b0 + i; if (idx < NN) s += deg[idx]; }
    part[t] = s;
    __syncthreads();
    for (int d = 1; d < 1024; d <<= 1) {
        unsigned v = (t >= d) ? part[t - d] : 0u;
        __syncthreads();
        part[t] += v;
        __syncthreads();
    }
    unsigned run = (t == 0) ? 0u : part[t - 1];
    for (int i = 0; i < CH; ++i) {
        int idx = b0 + i;
        if (idx < NN) { offs[idx] = run; cursor[idx] = run; run += deg[idx]; }
    }
    if (t == 1023) offs[NN] = EE;
}

__global__ void k_scatter(const int* __restrict__ ei, unsigned* __restrict__ cursor,
                          int* __restrict__ sorted_e) {
    int i = blockIdx.x * 256 + threadIdx.x;
    if (i < EE) {
        unsigned p = atomicAdd(&cursor[ei[EE + i]], 1u);
        sorted_e[p] = i;
    }
}

// ---- node GEMM: [NPAD x 256] @ [256 x 1024]^T(n-major) via bf16 MFMA ----
// 128x128 tile, 4 waves of 64x64, XOR-swizzled LDS (chunk c of row r at c^(r&7))
__global__ __launch_bounds__(256) void k_node_mfma(
        const ushort* __restrict__ xb, const ushort* __restrict__ Wnb,
        const float* __restrict__ bcat,
        ushort* __restrict__ qb, ushort* __restrict__ kb, ushort* __restrict__ vb,
        float* __restrict__ out) {
    __shared__ ushort As[128 * 64];
    __shared__ ushort Bs[128 * 64];
    int tid = threadIdx.x;
    int lane = tid & 63, wid = tid >> 6;
    int wr = wid >> 1, wc = wid & 1;
    int li = lane & 15, g = lane >> 4;
    int bm = blockIdx.x, bn = blockIdx.y;
    f32x4 acc[4][4] = {};
    for (int k0 = 0; k0 < 256; k0 += 64) {
        __syncthreads();
        #pragma unroll
        for (int i = 0; i < 4; ++i) {
            int ch = tid + i * 256;
            int r = ch >> 3, c = ch & 7;
            uint4 va = *(const uint4*)(xb + (size_t)(bm * 128 + r) * 256 + k0 + c * 8);
            *(uint4*)&As[r * 64 + ((c ^ (r & 7)) * 8)] = va;
            uint4 vb4 = *(const uint4*)(Wnb + (size_t)(bn * 128 + r) * 256 + k0 + c * 8);
            *(uint4*)&Bs[r * 64 + ((c ^ (r & 7)) * 8)] = vb4;
        }
        __syncthreads();
        #pragma unroll
        for (int kk = 0; kk < 2; ++kk) {
            bf16x8 a[4], b[4];
            #pragma unroll
            for (int m = 0; m < 4; ++m) {
                int r = wr * 64 + m * 16 + li;
                a[m] = *(const bf16x8*)&As[r * 64 + (((kk * 4 + g) ^ (r & 7)) * 8)];
            }
            #pragma unroll
            for (int n = 0; n < 4; ++n) {
                int r = wc * 64 + n * 16 + li;
                b[n] = *(const bf16x8*)&Bs[r * 64 + (((kk * 4 + g) ^ (r & 7)) * 8)];
            }
            #pragma unroll
            for (int m = 0; m < 4; ++m)
                #pragma unroll
                for (int n = 0; n < 4; ++n)
                    acc[m][n] = __builtin_amdgcn_mfma_f32_16x16x32_bf16(a[m], b[n], acc[m][n], 0, 0, 0);
        }
    }
    // epilogue: D layout row=(lane>>4)*4+reg, col=lane&15 (guide-verified)
    int sel = bn >> 1;
    int cbase = (bn & 1) * 128;
    ushort* dstb = (sel == 0) ? qb : (sel == 1) ? kb : vb;
    #pragma unroll
    for (int m = 0; m < 4; ++m) {
        #pragma unroll
        for (int r = 0; r < 4; ++r) {
            int row = bm * 128 + wr * 64 + m * 16 + g * 4 + r;
            if (row >= NN) continue;
            #pragma unroll
            for (int n = 0; n < 4; ++n) {
                int coll = wc * 64 + n * 16 + li;
                float val = acc[m][n][r] + bcat[bn * 128 + coll];
                int cin = cbase + coll;
                if (sel < 3) dstb[(size_t)row * 256 + cin] = f2b(val);
                else         out[(size_t)row * 256 + cin] = val;
            }
        }
    }
}

// ---- edge GEMM: e = ea @ We^T (64 edges x 256 cols/block) + fused alpha ----
// 4 waves: wave(wr,wc) owns edges [32wr,32wr+32) x cols [128wc,128wc+128)
// -> heads {2wc, 2wc+1} exclusively, so alpha reduces within one wave.
__global__ __launch_bounds__(256) void k_edge_mfma(
        const ushort* __restrict__ ea, const ushort* __restrict__ Web,
        const ushort* __restrict__ qb, const ushort* __restrict__ kb,
        const int* __restrict__ ei,
        ushort* __restrict__ ebuf, float* __restrict__ alpha) {
    __shared__ ushort As[64 * 64];
    __shared__ ushort Bs[256 * 64];
    __shared__ int s_src[64], s_dst[64];
    int tid = threadIdx.x;
    int lane = tid & 63, wid = tid >> 6;
    int wr = wid >> 1, wc = wid & 1;
    int li = lane & 15, g = lane >> 4;
    int e0 = blockIdx.x * 64;
    if (tid < 64) {
        int e = e0 + tid;
        if (e >= EE) e = EE - 1;  // clamp; tail edges never write
        s_src[tid] = ei[e];
        s_dst[tid] = ei[EE + e];
    }
    f32x4 acc[2][8] = {};
    for (int k0 = 0; k0 < 320; k0 += 64) {
        __syncthreads();
        #pragma unroll
        for (int i = 0; i < 2; ++i) {
            int ch = tid + i * 256;
            int r = ch >> 3, c = ch & 7;
            uint4 va = *(const uint4*)(ea + (size_t)(e0 + r) * 320 + k0 + c * 8);
            *(uint4*)&As[r * 64 + ((c ^ (r & 7)) * 8)] = va;
        }
        #pragma unroll
        for (int i = 0; i < 8; ++i) {
            int ch = tid + i * 256;
            int r = ch >> 3, c = ch & 7;
            uint4 vb4 = *(const uint4*)(Web + (size_t)r * 320 + k0 + c * 8);
            *(uint4*)&Bs[r * 64 + ((c ^ (r & 7)) * 8)] = vb4;
        }
        __syncthreads();
        #pragma unroll
        for (int kk = 0; kk < 2; ++kk) {
            bf16x8 a[2], b[8];
            #pragma unroll
            for (int m = 0; m < 2; ++m) {
                int r = wr * 32 + m * 16 + li;
                a[m] = *(const bf16x8*)&As[r * 64 + (((kk * 4 + g) ^ (r & 7)) * 8)];
            }
            #pragma unroll
            for (int n = 0; n < 8; ++n) {
                int r = wc * 128 + n * 16 + li;
                b[n] = *(const bf16x8*)&Bs[r * 64 + (((kk * 4 + g) ^ (r & 7)) * 8)];
            }
            #pragma unroll
            for (int m = 0; m < 2; ++m)
                #pragma unroll
                for (int n = 0; n < 8; ++n)
                    acc[m][n] = __builtin_amdgcn_mfma_f32_16x16x32_bf16(a[m], b[n], acc[m][n], 0, 0, 0);
        }
    }
    // epilogue: write e (bf16) and alpha = q[dst].(k[src]+e)/8 per head
    #pragma unroll
    for (int m = 0; m < 2; ++m) {
        #pragma unroll
        for (int r = 0; r < 4; ++r) {
            int el = wr * 32 + m * 16 + g * 4 + r;
            int edge = e0 + el;
            bool live = (edge < EE);
            int src = s_src[el], dst = s_dst[el];
            float p0 = 0.f, p1 = 0.f;
            #pragma unroll
            for (int n = 0; n < 8; ++n) {
                int col = wc * 128 + n * 16 + li;
                float ev = acc[m][n][r];
                if (live) ebuf[(size_t)edge * 256 + col] = f2b(ev);
                float qv = b2f(qb[(size_t)dst * 256 + col]);
                float kv = b2f(kb[(size_t)src * 256 + col]);
                float tt = qv * (kv + ev);
                if (n < 4) p0 += tt; else p1 += tt;
            }
            #pragma unroll
            for (int msk = 1; msk < 16; msk <<= 1) {
                p0 += __shfl_xor(p0, msk);
                p1 += __shfl_xor(p1, msk);
            }
            if (li < 2 && live) {
                float av = ((li == 0) ? p0 : p1) * 0.125f;
                int h = wc * 2 + li;
                alpha[(size_t)edge * 4 + h] = av;
            }
        }
    }
}

// ---- per-node gather: one wave per dst node, segment softmax + weighted sum,
// all in registers; no atomics. out = skip + sum(exp(a-m)*(v+e))/sum(exp) ----
__global__ __launch_bounds__(256) void k_gather(
        const ushort* __restrict__ ebuf, const ushort* __restrict__ vb,
        const float* __restrict__ alpha, const int* __restrict__ ei,
        const int* __restrict__ sorted_e, const unsigned* __restrict__ offs,
        float* __restrict__ out) {
    int wid = threadIdx.x >> 6, lane = threadIdx.x & 63;
    int n = blockIdx.x * 4 + wid;
    if (n >= NN) return;
    unsigned p0 = offs[n], p1 = offs[n + 1];
    if (p0 == p1) return;  // no in-edges: out stays = skip
    int h = lane >> 4;
    int c0 = lane * 4;
    // pass 1: per-head max over the segment
    float m = -INFINITY;
    for (unsigned p = p0; p < p1; ++p) {
        int e = sorted_e[p];
        m = fmaxf(m, alpha[(size_t)e * 4 + h]);
    }
    // pass 2: accumulate
    f32x4 acc = {0.f, 0.f, 0.f, 0.f};
    float denom = 0.f;
    for (unsigned p = p0; p < p1; ++p) {
        int e = sorted_e[p];
        int src = ei[e];
        float ex = __expf(alpha[(size_t)e * 4 + h] - m);
        ushort4 ev = *(const ushort4*)(ebuf + (size_t)e * 256 + c0);
        ushort4 vv = *(const ushort4*)(vb + (size_t)src * 256 + c0);
        acc[0] += (b2f(vv.x) + b2f(ev.x)) * ex;
        acc[1] += (b2f(vv.y) + b2f(ev.y)) * ex;
        acc[2] += (b2f(vv.z) + b2f(ev.z)) * ex;
        acc[3] += (b2f(vv.w) + b2f(ev.w)) * ex;
        denom += ex;
    }
    float inv = 1.f / (denom + 1e-16f);
    float4 o = *(float4*)(out + (size_t)n * 256 + c0);
    o.x += acc[0] * inv;
    o.y += acc[1] * inv;
    o.z += acc[2] * inv;
    o.w += acc[3] * inv;
    *(float4*)(out + (size_t)n * 256 + c0) = o;
}

extern "C" void kernel_launch(void* const* d_in, const int* in_sizes, int n_in,
                              void* d_out, int out_size, void* d_ws, size_t ws_size,
                              hipStream_t stream) {
    const float* x        = (const float*)d_in[0];
    const float* last_upd = (const float*)d_in[1];
    const float* t_arr    = (const float*)d_in[2];
    const float* msg      = (const float*)d_in[3];
    const int*   ei       = (const int*)d_in[4];
    const float* time_w   = (const float*)d_in[5];
    const float* time_b   = (const float*)d_in[6];
    const float* Wq = (const float*)d_in[7];  const float* bq = (const float*)d_in[8];
    const float* Wk = (const float*)d_in[9];  const float* bk = (const float*)d_in[10];
    const float* Wv = (const float*)d_in[11]; const float* bv = (const float*)d_in[12];
    const float* We = (const float*)d_in[13];
    const float* Wsk = (const float*)d_in[14]; const float* bsk = (const float*)d_in[15];
    float* out = (float*)d_out;
    char* base = (char*)d_ws;

    size_t off = 0;
    auto carve = [&](size_t bytes) {
        void* p = base + off;
        off += (bytes + 255) & ~(size_t)255;
        return p;
    };
    ushort* xb    = (ushort*)carve((size_t)NPAD * 256 * 2);
    ushort* Wnb   = (ushort*)carve((size_t)1024 * 256 * 2);
    ushort* Web   = (ushort*)carve((size_t)256 * 320 * 2);
    float*  bcat  = (float*) carve(1024 * 4);
    ushort* eab   = (ushort*)carve((size_t)EPAD * 320 * 2);
    ushort* qb    = (ushort*)carve((size_t)NN * 256 * 2);
    ushort* kb    = (ushort*)carve((size_t)NN * 256 * 2);
    ushort* vb    = (ushort*)carve((size_t)NN * 256 * 2);
    ushort* ebuf  = (ushort*)carve((size_t)EE * 256 * 2);
    float*  alpha = (float*) carve((size_t)EE * 4 * 4);
    unsigned* deg    = (unsigned*)carve((size_t)NN * 4);
    unsigned* cursor = (unsigned*)carve((size_t)NN * 4);
    unsigned* offs   = (unsigned*)carve((size_t)(NN + 1) * 4);
    int*      sorted = (int*)     carve((size_t)EE * 4);

    k_prep_w<<<dim3(512), dim3(256), 0, stream>>>(Wq, bq, Wk, bk, Wv, bv, Wsk, bsk, We,
                                                  Wnb, Web, bcat);
    k_prep_x<<<dim3(2048), dim3(256), 0, stream>>>(x, xb);
    k_prep_ea<<<dim3(4096), dim3(256), 0, stream>>>(msg, t_arr, last_upd, ei,
                                                    time_w, time_b, eab);
    k_zero<<<dim3((NN + 255) / 256), dim3(256), 0, stream>>>(deg);
    k_hist<<<dim3((EE + 255) / 256), dim3(256), 0, stream>>>(ei, deg);
    k_scan<<<dim3(1), dim3(1024), 0, stream>>>(deg, offs, cursor);
    k_scatter<<<dim3((EE + 255) / 256), dim3(256), 0, stream>>>(ei, cursor, sorted);
    k_node_mfma<<<dim3(391, 8), dim3(256), 0, stream>>>(xb, Wnb, bcat, qb, kb, vb, out);
    k_edge_mfma<<<dim3(3907), dim3(256), 0, stream>>>(eab, Web, qb, kb, ei,
                                                      ebuf, alpha);
    k_gather<<<dim3((NN + 3) / 4), dim3(256), 0, stream>>>(ebuf, vb, alpha, ei,
                                                           sorted, offs, out);
}

// Round 4
// 621.027 us; speedup vs baseline: 5.0637x; 1.0466x over previous
//
#include <hip/hip_runtime.h>
#include <math.h>

#define NN 50000
#define EE 250000
#define NPAD 50048

typedef float f32x4 __attribute__((ext_vector_type(4)));
typedef __bf16 bf16x8 __attribute__((ext_vector_type(8)));

// f32 -> bf16 (RNE) and back, header-independent
static __device__ __forceinline__ ushort f2b(float f) {
    unsigned u = __float_as_uint(f);
    unsigned r = (u + 0x7FFFu + ((u >> 16) & 1u)) >> 16;
    return (ushort)r;
}
static __device__ __forceinline__ float b2f(ushort u) {
    return __uint_as_float(((unsigned)u) << 16);
}

// ---- weights -> bf16 (W stays [out][in] = [n][k]; B-fragments want n-major) ----
__global__ void k_prep_w(const float* __restrict__ Wq, const float* __restrict__ bq,
                         const float* __restrict__ Wk, const float* __restrict__ bk,
                         const float* __restrict__ Wv, const float* __restrict__ bv,
                         const float* __restrict__ Wskip, const float* __restrict__ bskip,
                         const float* __restrict__ We,
                         ushort* __restrict__ Wnb, ushort* __restrict__ Web,
                         float* __restrict__ bcat) {
    int i = blockIdx.x * 256 + threadIdx.x;
    int st = gridDim.x * 256;
    for (int idx = i; idx < 1024 * 256; idx += st) {
        int n = idx >> 8, kk = idx & 255;
        int sel = n >> 8, o = n & 255;
        const float* W = (sel == 0) ? Wq : (sel == 1) ? Wk : (sel == 2) ? Wv : Wskip;
        Wnb[idx] = f2b(W[o * 256 + kk]);
    }
    for (int idx = i; idx < 256 * 320; idx += st) Web[idx] = f2b(We[idx]);
    for (int idx = i; idx < 1024; idx += st) {
        int sel = idx >> 8, o = idx & 255;
        const float* b = (sel == 0) ? bq : (sel == 1) ? bk : (sel == 2) ? bv : bskip;
        bcat[idx] = b[o];
    }
}

// ---- counting sort by dst: zero -> hist -> scan -> scatter ----
__global__ void k_zero(unsigned* __restrict__ deg) {
    int i = blockIdx.x * 256 + threadIdx.x;
    if (i < NN) deg[i] = 0u;
}

__global__ void k_hist(const int* __restrict__ ei, unsigned* __restrict__ deg) {
    int i = blockIdx.x * 256 + threadIdx.x;
    if (i < EE) atomicAdd(&deg[ei[EE + i]], 1u);
}

__global__ __launch_bounds__(1024) void k_scan(const unsigned* __restrict__ deg,
                                               unsigned* __restrict__ offs,
                                               unsigned* __restrict__ cursor) {
    __shared__ unsigned part[1024];
    int t = threadIdx.x;
    const int CH = (NN + 1023) / 1024;  // 49
    int b0 = t * CH;
    unsigned s = 0;
    for (int i = 0; i < CH; ++i) { int idx = b0 + i; if (idx < NN) s += deg[idx]; }
    part[t] = s;
    __syncthreads();
    for (int d = 1; d < 1024; d <<= 1) {
        unsigned v = (t >= d) ? part[t - d] : 0u;
        __syncthreads();
        part[t] += v;
        __syncthreads();
    }
    unsigned run = (t == 0) ? 0u : part[t - 1];
    for (int i = 0; i < CH; ++i) {
        int idx = b0 + i;
        if (idx < NN) { offs[idx] = run; cursor[idx] = run; run += deg[idx]; }
    }
    if (t == 1023) offs[NN] = EE;
}

__global__ void k_scatter(const int* __restrict__ ei, unsigned* __restrict__ cursor,
                          int* __restrict__ sorted_e) {
    int i = blockIdx.x * 256 + threadIdx.x;
    if (i < EE) {
        unsigned p = atomicAdd(&cursor[ei[EE + i]], 1u);
        sorted_e[p] = i;
    }
}

// ---- node GEMM: [NPAD x 256](x, f32->bf16 on the fly) @ [256 x 1024]^T ----
// 128x128 tile, 4 waves of 64x64, XOR-swizzled LDS (chunk c of row r at c^(r&7))
__global__ __launch_bounds__(256) void k_node_mfma(
        const float* __restrict__ x, const ushort* __restrict__ Wnb,
        const float* __restrict__ bcat,
        ushort* __restrict__ qb, ushort* __restrict__ kb, ushort* __restrict__ vb,
        float* __restrict__ out) {
    __shared__ ushort As[128 * 64];
    __shared__ ushort Bs[128 * 64];
    int tid = threadIdx.x;
    int lane = tid & 63, wid = tid >> 6;
    int wr = wid >> 1, wc = wid & 1;
    int li = lane & 15, g = lane >> 4;
    int bm = blockIdx.x, bn = blockIdx.y;
    f32x4 acc[4][4] = {};
    for (int k0 = 0; k0 < 256; k0 += 64) {
        __syncthreads();
        #pragma unroll
        for (int i = 0; i < 4; ++i) {
            int ch = tid + i * 256;
            int r = ch >> 3, c = ch & 7;
            int row = bm * 128 + r;
            union { ushort u[8]; uint4 v; } s;
            if (row < NN) {
                const float* xr = x + (size_t)row * 256 + k0 + c * 8;
                float4 a = *(const float4*)xr;
                float4 b = *(const float4*)(xr + 4);
                s.u[0] = f2b(a.x); s.u[1] = f2b(a.y); s.u[2] = f2b(a.z); s.u[3] = f2b(a.w);
                s.u[4] = f2b(b.x); s.u[5] = f2b(b.y); s.u[6] = f2b(b.z); s.u[7] = f2b(b.w);
            } else {
                s.v = make_uint4(0, 0, 0, 0);
            }
            *(uint4*)&As[r * 64 + ((c ^ (r & 7)) * 8)] = s.v;
            uint4 vb4 = *(const uint4*)(Wnb + (size_t)(bn * 128 + r) * 256 + k0 + c * 8);
            *(uint4*)&Bs[r * 64 + ((c ^ (r & 7)) * 8)] = vb4;
        }
        __syncthreads();
        #pragma unroll
        for (int kk = 0; kk < 2; ++kk) {
            bf16x8 a[4], b[4];
            #pragma unroll
            for (int m = 0; m < 4; ++m) {
                int r = wr * 64 + m * 16 + li;
                a[m] = *(const bf16x8*)&As[r * 64 + (((kk * 4 + g) ^ (r & 7)) * 8)];
            }
            #pragma unroll
            for (int n = 0; n < 4; ++n) {
                int r = wc * 64 + n * 16 + li;
                b[n] = *(const bf16x8*)&Bs[r * 64 + (((kk * 4 + g) ^ (r & 7)) * 8)];
            }
            #pragma unroll
            for (int m = 0; m < 4; ++m)
                #pragma unroll
                for (int n = 0; n < 4; ++n)
                    acc[m][n] = __builtin_amdgcn_mfma_f32_16x16x32_bf16(a[m], b[n], acc[m][n], 0, 0, 0);
        }
    }
    // epilogue: D layout row=(lane>>4)*4+reg, col=lane&15 (guide-verified)
    int sel = bn >> 1;
    int cbase = (bn & 1) * 128;
    ushort* dstb = (sel == 0) ? qb : (sel == 1) ? kb : vb;
    #pragma unroll
    for (int m = 0; m < 4; ++m) {
        #pragma unroll
        for (int r = 0; r < 4; ++r) {
            int row = bm * 128 + wr * 64 + m * 16 + g * 4 + r;
            if (row >= NN) continue;
            #pragma unroll
            for (int n = 0; n < 4; ++n) {
                int coll = wc * 64 + n * 16 + li;
                float val = acc[m][n][r] + bcat[bn * 128 + coll];
                int cin = cbase + coll;
                if (sel < 3) dstb[(size_t)row * 256 + cin] = f2b(val);
                else         out[(size_t)row * 256 + cin] = val;
            }
        }
    }
}

// ---- edge GEMM: e = [cos(rel_t*w+b) | msg] @ We^T, fused time-enc + alpha ----
// 64 edges x 256 cols/block. 4 waves: wave(wr,wc) owns edges [32wr,+32) x cols
// [128wc,+128) -> heads {2wc,2wc+1}; alpha reduces within one wave.
// Epilogue stages k[src]/q[dst] rows via LDS (vectorized) to kill scalar gathers.
__global__ __launch_bounds__(256) void k_edge_mfma(
        const float* __restrict__ msg, const float* __restrict__ t_arr,
        const float* __restrict__ lu, const float* __restrict__ tw,
        const float* __restrict__ tb, const ushort* __restrict__ Web,
        const ushort* __restrict__ qb, const ushort* __restrict__ kb,
        const int* __restrict__ ei,
        ushort* __restrict__ ebuf, float* __restrict__ alpha) {
    __shared__ ushort SS[64 * 328];  // main loop: A=[0,4096) B=[4096,20480); epi: 64x328
    __shared__ int s_src[64], s_dst[64];
    __shared__ float s_relt[64];
    int tid = threadIdx.x;
    int lane = tid & 63, wid = tid >> 6;
    int wr = wid >> 1, wc = wid & 1;
    int li = lane & 15, g = lane >> 4;
    int e0 = blockIdx.x * 64;
    if (tid < 64) {
        int e = e0 + tid;
        if (e >= EE) e = EE - 1;  // clamp; tail edges never write
        int s = ei[e];
        s_src[tid] = s;
        s_dst[tid] = ei[EE + e];
        s_relt[tid] = lu[s] - t_arr[e];
    }
    f32x4 acc[2][8] = {};
    for (int k0 = 0; k0 < 320; k0 += 64) {
        __syncthreads();
        #pragma unroll
        for (int i = 0; i < 2; ++i) {
            int ch = tid + i * 256;
            int r = ch >> 3, c = ch & 7;
            union { ushort u[8]; uint4 v; } s;
            if (k0 == 0) {  // time-encoding cols 0..63
                float rt = s_relt[r];
                #pragma unroll
                for (int j = 0; j < 8; ++j)
                    s.u[j] = f2b(cosf(rt * tw[c * 8 + j] + tb[c * 8 + j]));
            } else {        // msg cols (k0-64)..(k0-1)
                int erow = e0 + r; if (erow >= EE) erow = EE - 1;
                const float* mrow = msg + (size_t)erow * 256 + (k0 - 64) + c * 8;
                float4 a = *(const float4*)mrow;
                float4 b = *(const float4*)(mrow + 4);
                s.u[0] = f2b(a.x); s.u[1] = f2b(a.y); s.u[2] = f2b(a.z); s.u[3] = f2b(a.w);
                s.u[4] = f2b(b.x); s.u[5] = f2b(b.y); s.u[6] = f2b(b.z); s.u[7] = f2b(b.w);
            }
            *(uint4*)&SS[r * 64 + ((c ^ (r & 7)) * 8)] = s.v;
        }
        #pragma unroll
        for (int i = 0; i < 8; ++i) {
            int ch = tid + i * 256;
            int r = ch >> 3, c = ch & 7;
            uint4 vb4 = *(const uint4*)(Web + (size_t)r * 320 + k0 + c * 8);
            *(uint4*)&SS[4096 + r * 64 + ((c ^ (r & 7)) * 8)] = vb4;
        }
        __syncthreads();
        #pragma unroll
        for (int kk = 0; kk < 2; ++kk) {
            bf16x8 a[2], b[8];
            #pragma unroll
            for (int m = 0; m < 2; ++m) {
                int r = wr * 32 + m * 16 + li;
                a[m] = *(const bf16x8*)&SS[r * 64 + (((kk * 4 + g) ^ (r & 7)) * 8)];
            }
            #pragma unroll
            for (int n = 0; n < 8; ++n) {
                int r = wc * 128 + n * 16 + li;
                b[n] = *(const bf16x8*)&SS[4096 + r * 64 + (((kk * 4 + g) ^ (r & 7)) * 8)];
            }
            #pragma unroll
            for (int m = 0; m < 2; ++m)
                #pragma unroll
                for (int n = 0; n < 8; ++n)
                    acc[m][n] = __builtin_amdgcn_mfma_f32_16x16x32_bf16(a[m], b[n], acc[m][n], 0, 0, 0);
        }
    }
    // ---- epilogue ----
    // 1) write e (acc holds pure e values)
    #pragma unroll
    for (int m = 0; m < 2; ++m) {
        #pragma unroll
        for (int r = 0; r < 4; ++r) {
            int el = wr * 32 + m * 16 + g * 4 + r;
            int edge = e0 + el;
            if (edge >= EE) continue;
            #pragma unroll
            for (int n = 0; n < 8; ++n) {
                int col = wc * 128 + n * 16 + li;
                ebuf[(size_t)edge * 256 + col] = f2b(acc[m][n][r]);
            }
        }
    }
    // 2) stage k[src] rows (64 x 256 bf16, padded stride 328) and add into acc
    __syncthreads();
    #pragma unroll
    for (int i = 0; i < 8; ++i) {
        int idx = tid + i * 256;
        int r = idx >> 5, c = idx & 31;
        uint4 kv = *(const uint4*)(kb + (size_t)s_src[r] * 256 + c * 8);
        *(uint4*)&SS[r * 328 + c * 8] = kv;
    }
    __syncthreads();
    #pragma unroll
    for (int m = 0; m < 2; ++m)
        #pragma unroll
        for (int r = 0; r < 4; ++r) {
            int el = wr * 32 + m * 16 + g * 4 + r;
            #pragma unroll
            for (int n = 0; n < 8; ++n)
                acc[m][n][r] += b2f(SS[el * 328 + wc * 128 + n * 16 + li]);
        }
    // 3) stage q[dst] rows, dot with (k+e), reduce, write alpha
    __syncthreads();
    #pragma unroll
    for (int i = 0; i < 8; ++i) {
        int idx = tid + i * 256;
        int r = idx >> 5, c = idx & 31;
        uint4 qv = *(const uint4*)(qb + (size_t)s_dst[r] * 256 + c * 8);
        *(uint4*)&SS[r * 328 + c * 8] = qv;
    }
    __syncthreads();
    #pragma unroll
    for (int m = 0; m < 2; ++m) {
        #pragma unroll
        for (int r = 0; r < 4; ++r) {
            int el = wr * 32 + m * 16 + g * 4 + r;
            int edge = e0 + el;
            float p0 = 0.f, p1 = 0.f;
            #pragma unroll
            for (int n = 0; n < 8; ++n) {
                float qv = b2f(SS[el * 328 + wc * 128 + n * 16 + li]);
                float tt = qv * acc[m][n][r];
                if (n < 4) p0 += tt; else p1 += tt;
            }
            #pragma unroll
            for (int msk = 1; msk < 16; msk <<= 1) {
                p0 += __shfl_xor(p0, msk);
                p1 += __shfl_xor(p1, msk);
            }
            if (li < 2 && edge < EE) {
                float av = ((li == 0) ? p0 : p1) * 0.125f;
                int h = wc * 2 + li;
                alpha[(size_t)edge * 4 + h] = av;
            }
        }
    }
}

// ---- per-node gather: one wave per dst node, segment softmax + weighted sum,
// all in registers; no atomics. out = skip + sum(exp(a-m)*(v+e))/sum(exp) ----
__global__ __launch_bounds__(256) void k_gather(
        const ushort* __restrict__ ebuf, const ushort* __restrict__ vb,
        const float* __restrict__ alpha, const int* __restrict__ ei,
        const int* __restrict__ sorted_e, const unsigned* __restrict__ offs,
        float* __restrict__ out) {
    int wid = threadIdx.x >> 6, lane = threadIdx.x & 63;
    int n = blockIdx.x * 4 + wid;
    if (n >= NN) return;
    unsigned p0 = offs[n], p1 = offs[n + 1];
    if (p0 == p1) return;  // no in-edges: out stays = skip
    int h = lane >> 4;
    int c0 = lane * 4;
    // pass 1: per-head max over the segment
    float m = -INFINITY;
    for (unsigned p = p0; p < p1; ++p) {
        int e = sorted_e[p];
        m = fmaxf(m, alpha[(size_t)e * 4 + h]);
    }
    // pass 2: accumulate
    f32x4 acc = {0.f, 0.f, 0.f, 0.f};
    float denom = 0.f;
    for (unsigned p = p0; p < p1; ++p) {
        int e = sorted_e[p];
        int src = ei[e];
        float ex = __expf(alpha[(size_t)e * 4 + h] - m);
        ushort4 ev = *(const ushort4*)(ebuf + (size_t)e * 256 + c0);
        ushort4 vv = *(const ushort4*)(vb + (size_t)src * 256 + c0);
        acc[0] += (b2f(vv.x) + b2f(ev.x)) * ex;
        acc[1] += (b2f(vv.y) + b2f(ev.y)) * ex;
        acc[2] += (b2f(vv.z) + b2f(ev.z)) * ex;
        acc[3] += (b2f(vv.w) + b2f(ev.w)) * ex;
        denom += ex;
    }
    float inv = 1.f / (denom + 1e-16f);
    float4 o = *(float4*)(out + (size_t)n * 256 + c0);
    o.x += acc[0] * inv;
    o.y += acc[1] * inv;
    o.z += acc[2] * inv;
    o.w += acc[3] * inv;
    *(float4*)(out + (size_t)n * 256 + c0) = o;
}

extern "C" void kernel_launch(void* const* d_in, const int* in_sizes, int n_in,
                              void* d_out, int out_size, void* d_ws, size_t ws_size,
                              hipStream_t stream) {
    const float* x        = (const float*)d_in[0];
    const float* last_upd = (const float*)d_in[1];
    const float* t_arr    = (const float*)d_in[2];
    const float* msg      = (const float*)d_in[3];
    const int*   ei       = (const int*)d_in[4];
    const float* time_w   = (const float*)d_in[5];
    const float* time_b   = (const float*)d_in[6];
    const float* Wq = (const float*)d_in[7];  const float* bq = (const float*)d_in[8];
    const float* Wk = (const float*)d_in[9];  const float* bk = (const float*)d_in[10];
    const float* Wv = (const float*)d_in[11]; const float* bv = (const float*)d_in[12];
    const float* We = (const float*)d_in[13];
    const float* Wsk = (const float*)d_in[14]; const float* bsk = (const float*)d_in[15];
    float* out = (float*)d_out;
    char* base = (char*)d_ws;

    size_t off = 0;
    auto carve = [&](size_t bytes) {
        void* p = base + off;
        off += (bytes + 255) & ~(size_t)255;
        return p;
    };
    ushort* Wnb   = (ushort*)carve((size_t)1024 * 256 * 2);
    ushort* Web   = (ushort*)carve((size_t)256 * 320 * 2);
    float*  bcat  = (float*) carve(1024 * 4);
    ushort* qb    = (ushort*)carve((size_t)NN * 256 * 2);
    ushort* kb    = (ushort*)carve((size_t)NN * 256 * 2);
    ushort* vb    = (ushort*)carve((size_t)NN * 256 * 2);
    ushort* ebuf  = (ushort*)carve((size_t)EE * 256 * 2);
    float*  alpha = (float*) carve((size_t)EE * 4 * 4);
    unsigned* deg    = (unsigned*)carve((size_t)NN * 4);
    unsigned* cursor = (unsigned*)carve((size_t)NN * 4);
    unsigned* offs   = (unsigned*)carve((size_t)(NN + 1) * 4);
    int*      sorted = (int*)     carve((size_t)EE * 4);

    k_prep_w<<<dim3(512), dim3(256), 0, stream>>>(Wq, bq, Wk, bk, Wv, bv, Wsk, bsk, We,
                                                  Wnb, Web, bcat);
    k_zero<<<dim3((NN + 255) / 256), dim3(256), 0, stream>>>(deg);
    k_hist<<<dim3((EE + 255) / 256), dim3(256), 0, stream>>>(ei, deg);
    k_scan<<<dim3(1), dim3(1024), 0, stream>>>(deg, offs, cursor);
    k_scatter<<<dim3((EE + 255) / 256), dim3(256), 0, stream>>>(ei, cursor, sorted);
    k_node_mfma<<<dim3(391, 8), dim3(256), 0, stream>>>(x, Wnb, bcat, qb, kb, vb, out);
    k_edge_mfma<<<dim3(3907), dim3(256), 0, stream>>>(msg, t_arr, last_upd,
                                                      time_w, time_b, Web, qb, kb, ei,
                                                      ebuf, alpha);
    k_gather<<<dim3((NN + 3) / 4), dim3(256), 0, stream>>>(ebuf, vb, alpha, ei,
                                                           sorted, offs, out);
}